// Round 6
// baseline (507.717 us; speedup 1.0000x reference)
//
#include <hip/hip_runtime.h>
#include <math.h>

#define BN 8192
#define DD 4096
#define RK 16
#define HIDN 24
#define NCHUNK 128

// ws layout (float offsets). Only cvec (16 floats) needs zero-init.
#define OFF_T0TP 0                            // 4*16*BN  = 524288
#define OFF_T1TP (OFF_T0TP + 4*RK*BN)         // 32*16*BN = 4194304
#define OFF_HTP  (OFF_T1TP + 32*RK*BN)        // 4*32*BN  = 1048576
#define OFF_T1T  (OFF_HTP + 4*32*BN)          // 16*BN    = 131072
#define OFF_PS   (OFF_T1T + RK*BN)            // 524288
#define OFF_PQ   (OFF_PS + NCHUNK*DD)         // 524288
#define OFF_V1T  (OFF_PQ + NCHUNK*DD)         // 65536
#define OFF_MEAN (OFF_V1T + DD*RK)            // 4096
#define OFF_INV  (OFF_MEAN + DD)              // 4096
#define OFF_C    (OFF_INV + DD)               // 16 (zeroed)
#define OFF_V0PH (OFF_C + 16)                 // 16*4096 bf16 = 32768 floats
#define OFF_V0PL (OFF_V0PH + RK*DD/2)         // 32768
#define OFF_W1H  (OFF_V0PL + RK*DD/2)         // 24*4096 bf16 = 49152 floats
#define OFF_W1L  (OFF_W1H + HIDN*DD/2)        // 49152
// total ~7.2M floats = 28.7 MB

typedef __attribute__((ext_vector_type(8))) __bf16 bf16x8;
typedef __attribute__((ext_vector_type(4))) float f32x4;

// f32x8 -> bf16 hi + residual-lo frags (RNE via compiler casts)
__device__ inline void split8(const float* p, bf16x8& hi, bf16x8& lo) {
    float4 a = *(const float4*)p;
    float4 b = *(const float4*)(p + 4);
    float v[8] = {a.x, a.y, a.z, a.w, b.x, b.y, b.z, b.w};
#pragma unroll
    for (int j = 0; j < 8; ++j) {
        __bf16 h = (__bf16)v[j];
        hi[j] = h;
        lo[j] = (__bf16)(v[j] - (float)h);
    }
}

// ---------------- K0w: pre-split w1 -> bf16 hi/lo ---------------------------
__global__ __launch_bounds__(256) void k0w(const float* __restrict__ w1,
                                           __bf16* __restrict__ w1h,
                                           __bf16* __restrict__ w1l) {
    int i = (blockIdx.x * 256 + threadIdx.x) * 4;     // 96 blocks -> 98304 elems
    float4 v = *(const float4*)(w1 + i);
    float vv[4] = {v.x, v.y, v.z, v.w};
#pragma unroll
    for (int j = 0; j < 4; ++j) {
        __bf16 h = (__bf16)vv[j];
        w1h[i + j] = h;
        w1l[i + j] = (__bf16)(vv[j] - (float)h);
    }
}

// ---------------- K1a: per-column partial sums, float4, 64-row chunks -------
__global__ __launch_bounds__(256) void k1a(const float* __restrict__ g,
                                           float* __restrict__ ps,
                                           float* __restrict__ pq) {
    int ct = blockIdx.x & 3, rc = blockIdx.x >> 2;   // 4 col-tiles x 128 chunks
    int col = ct * 1024 + threadIdx.x * 4;
    size_t base = (size_t)rc * 64 * DD + col;
    float4 s1 = make_float4(0.f, 0.f, 0.f, 0.f);
    float4 s2 = make_float4(0.f, 0.f, 0.f, 0.f);
#pragma unroll 8
    for (int i = 0; i < 64; ++i) {
        float4 v = *(const float4*)(g + base + (size_t)i * DD);
        s1.x += v.x; s1.y += v.y; s1.z += v.z; s1.w += v.w;
        s2.x = fmaf(v.x, v.x, s2.x);
        s2.y = fmaf(v.y, v.y, s2.y);
        s2.z = fmaf(v.z, v.z, s2.z);
        s2.w = fmaf(v.w, v.w, s2.w);
    }
    *(float4*)(ps + (size_t)rc * DD + col) = s1;
    *(float4*)(pq + (size_t)rc * DD + col) = s2;
}

// ---------------- K1bT: stats + v1 transpose + v0p split + c partials -------
// v0p = v0*diag(inv) pre-split to bf16 hi/lo; c[r] = sum_d v0p[r][d]*mean[d].
__global__ __launch_bounds__(256) void k1bT(const float* __restrict__ ps,
                                            const float* __restrict__ pq,
                                            const float* __restrict__ v1,
                                            const float* __restrict__ v0,
                                            float* __restrict__ meanw,
                                            float* __restrict__ invw,
                                            float* __restrict__ v1T,
                                            __bf16* __restrict__ v0ph,
                                            __bf16* __restrict__ v0pl,
                                            float* __restrict__ cvec) {
    __shared__ float csum[16];
    int tid = threadIdx.x;
    int d = blockIdx.x * 256 + tid;
    if (tid < 16) csum[tid] = 0.f;
    __syncthreads();
    float s1 = 0.f, s2 = 0.f;
#pragma unroll 8
    for (int i = 0; i < NCHUNK; ++i) {
        s1 += ps[i * DD + d];
        s2 += pq[i * DD + d];
    }
    float mean = s1 / (float)BN;
    float var = (s2 - s1 * s1 / (float)BN) / (float)(BN - 1);
    var = fmaxf(var, 0.f);
    float invv = 1.f / (sqrtf(var) + 1e-7f);
    meanw[d] = mean;
    invw[d] = invv;
    // v1 transpose
    float v[16];
#pragma unroll
    for (int s = 0; s < 16; ++s) v[s] = v1[(size_t)s * DD + d];
#pragma unroll
    for (int s = 0; s < 4; ++s)
        *(float4*)(v1T + (size_t)d * 16 + s * 4) =
            make_float4(v[4 * s], v[4 * s + 1], v[4 * s + 2], v[4 * s + 3]);
    // v0p split + c partials
    float pc[16];
#pragma unroll
    for (int r = 0; r < 16; ++r) {
        float vp = v0[(size_t)r * DD + d] * invv;
        __bf16 h = (__bf16)vp;
        v0ph[(size_t)r * DD + d] = h;
        v0pl[(size_t)r * DD + d] = (__bf16)(vp - (float)h);
        pc[r] = vp * mean;
    }
#pragma unroll
    for (int r = 0; r < 16; ++r) {
        float x = pc[r];
#pragma unroll
        for (int off = 1; off < 64; off <<= 1) x += __shfl_xor(x, off);
        if ((tid & 63) == 0) atomicAdd(&csum[r], x);
    }
    __syncthreads();
    if (tid < 16) atomicAdd(&cvec[tid], csum[tid]);
}

// ---------------- K2m: MFMA  T0Tp[q][r][b] = v0p · g  (raw grad, no atomics)
__global__ __launch_bounds__(256) void k2m(const float* __restrict__ grad,
                                           const __bf16* __restrict__ v0ph,
                                           const __bf16* __restrict__ v0pl,
                                           float* __restrict__ T0Tp) {
    __shared__ float red[4][256];
    int tid = threadIdx.x;
    int wv = tid >> 6, l = tid & 63;
    int lr = l & 15, lk = l >> 4;
    int m0 = (blockIdx.x >> 2) * 16;
    int q = blockIdx.x & 3;
    int kbase = q * 1024 + wv * 256;
    const float* g0 = grad + (size_t)(m0 + lr) * DD + kbase + lk * 8;
    const __bf16* vph = v0ph + (size_t)lr * DD + kbase + lk * 8;
    const __bf16* vpl = v0pl + (size_t)lr * DD + kbase + lk * 8;
    f32x4 acc = {0.f, 0.f, 0.f, 0.f};
#pragma unroll 2
    for (int ks = 0; ks < 8; ++ks) {
        int k0 = ks * 32;
        bf16x8 vhi = *(const bf16x8*)(vph + k0);
        bf16x8 vlo = *(const bf16x8*)(vpl + k0);
        bf16x8 ghi, glo;
        split8(g0 + k0, ghi, glo);
        acc = __builtin_amdgcn_mfma_f32_16x16x32_bf16(vhi, ghi, acc, 0, 0, 0);
        acc = __builtin_amdgcn_mfma_f32_16x16x32_bf16(vhi, glo, acc, 0, 0, 0);
        acc = __builtin_amdgcn_mfma_f32_16x16x32_bf16(vlo, ghi, acc, 0, 0, 0);
    }
#pragma unroll
    for (int r = 0; r < 4; ++r)
        red[wv][(lk * 4 + r) * 16 + lr] = acc[r];
    __syncthreads();
    float s = red[0][tid] + red[1][tid] + red[2][tid] + red[3][tid];
    T0Tp[(size_t)(q * 16 + (tid >> 4)) * BN + m0 + (tid & 15)] = s;
}

// ---------------- K3: T1Tp[dt][s][b] = v1T·relu(b0+u0·t0)  (no atomics) -----
__global__ __launch_bounds__(256) void k3(const float* __restrict__ T0Tp,
                                          const float* __restrict__ cvec,
                                          const float* __restrict__ u0,
                                          const float* __restrict__ b0,
                                          const float* __restrict__ v1T,
                                          float* __restrict__ T1Tp) {
    int b = (blockIdx.x >> 5) * 256 + threadIdx.x;
    int dt = blockIdx.x & 31;
    int d0 = dt * 128;
    float t0[16];
#pragma unroll
    for (int r = 0; r < 16; ++r)
        t0[r] = T0Tp[(size_t)r * BN + b] + T0Tp[(size_t)(16 + r) * BN + b] +
                T0Tp[(size_t)(32 + r) * BN + b] + T0Tp[(size_t)(48 + r) * BN + b] -
                cvec[r];
    float acc[16];
#pragma unroll
    for (int s = 0; s < 16; ++s) acc[s] = 0.f;
#pragma unroll 2
    for (int d = d0; d < d0 + 128; ++d) {
        const float* ur = u0 + (size_t)d * RK;       // uniform
        float x1 = b0[d];
#pragma unroll
        for (int r = 0; r < 16; ++r) x1 = fmaf(ur[r], t0[r], x1);
        x1 = fmaxf(x1, 0.f);
        const float* vr = v1T + (size_t)d * RK;      // uniform
#pragma unroll
        for (int s = 0; s < 16; ++s) acc[s] = fmaf(vr[s], x1, acc[s]);
    }
#pragma unroll
    for (int s = 0; s < 16; ++s)
        T1Tp[(size_t)(dt * 16 + s) * BN + b] = acc[s];
}

// ---------------- K3r: T1T[r][b] = sum_dt T1Tp[dt][r][b] --------------------
__global__ __launch_bounds__(256) void k3r(const float* __restrict__ T1Tp,
                                           float* __restrict__ T1T) {
    int idx = blockIdx.x * 256 + threadIdx.x;        // 512 blocks -> 131072
    int r = idx >> 13, b = idx & 8191;
    float s = 0.f;
#pragma unroll 8
    for (int p = 0; p < 32; ++p) s += T1Tp[(size_t)(p * 16 + r) * BN + b];
    T1T[(size_t)r * BN + b] = s;
}

// ---------------- K5m: MFMA  HTp[q][j][b] = w1 · embed^T  (no atomics) ------
__global__ __launch_bounds__(256) void k5m(const float* __restrict__ embed,
                                           const __bf16* __restrict__ w1h,
                                           const __bf16* __restrict__ w1l,
                                           float* __restrict__ HTp) {
    __shared__ float red[4][512];
    int tid = threadIdx.x;
    int wv = tid >> 6, l = tid & 63;
    int lr = l & 15, lk = l >> 4;
    int m0 = (blockIdx.x >> 2) * 16;
    int q = blockIdx.x & 3;
    int kbase = q * 1024 + wv * 256;
    int wr1 = (lr + 16 > 23) ? 23 : lr + 16;         // clamp pad rows
    const float* e0 = embed + (size_t)(m0 + lr) * DD + kbase + lk * 8;
    const __bf16* wha = w1h + (size_t)lr * DD + kbase + lk * 8;
    const __bf16* wla = w1l + (size_t)lr * DD + kbase + lk * 8;
    const __bf16* whb = w1h + (size_t)wr1 * DD + kbase + lk * 8;
    const __bf16* wlb = w1l + (size_t)wr1 * DD + kbase + lk * 8;
    f32x4 acc0 = {0.f, 0.f, 0.f, 0.f};
    f32x4 acc1 = {0.f, 0.f, 0.f, 0.f};
#pragma unroll 2
    for (int ks = 0; ks < 8; ++ks) {
        int k0 = ks * 32;
        bf16x8 whi0 = *(const bf16x8*)(wha + k0);
        bf16x8 wlo0 = *(const bf16x8*)(wla + k0);
        bf16x8 whi1 = *(const bf16x8*)(whb + k0);
        bf16x8 wlo1 = *(const bf16x8*)(wlb + k0);
        bf16x8 ehi, elo;
        split8(e0 + k0, ehi, elo);
        acc0 = __builtin_amdgcn_mfma_f32_16x16x32_bf16(whi0, ehi, acc0, 0, 0, 0);
        acc1 = __builtin_amdgcn_mfma_f32_16x16x32_bf16(whi1, ehi, acc1, 0, 0, 0);
        acc0 = __builtin_amdgcn_mfma_f32_16x16x32_bf16(whi0, elo, acc0, 0, 0, 0);
        acc1 = __builtin_amdgcn_mfma_f32_16x16x32_bf16(whi1, elo, acc1, 0, 0, 0);
        acc0 = __builtin_amdgcn_mfma_f32_16x16x32_bf16(wlo0, ehi, acc0, 0, 0, 0);
        acc1 = __builtin_amdgcn_mfma_f32_16x16x32_bf16(wlo1, ehi, acc1, 0, 0, 0);
    }
#pragma unroll
    for (int r = 0; r < 4; ++r) {
        red[wv][(lk * 4 + r) * 16 + lr] = acc0[r];
        red[wv][256 + (lk * 4 + r) * 16 + lr] = acc1[r];
    }
    __syncthreads();
#pragma unroll
    for (int j = 0; j < 2; ++j) {
        int idx = tid + j * 256;
        float s = red[0][idx] + red[1][idx] + red[2][idx] + red[3][idx];
        int nt = idx >> 8, nr = (idx >> 4) & 15, cc = idx & 15;
        HTp[(size_t)(q * 32 + nt * 16 + nr) * BN + m0 + cc] = s;
    }
}

__device__ inline float dotu(const float4* ur, const float* t, float b) {
    float a = b;
#pragma unroll
    for (int rr = 0; rr < 4; ++rr) {
        a = fmaf(ur[rr].x, t[4 * rr + 0], a);
        a = fmaf(ur[rr].y, t[4 * rr + 1], a);
        a = fmaf(ur[rr].z, t[4 * rr + 2], a);
        a = fmaf(ur[rr].w, t[4 * rr + 3], a);
    }
    return a;
}

// ---------------- K6fc: coeff head (HTp-sum) + row norms + blend + store ----
__global__ __launch_bounds__(1024) void k6fc(const float* __restrict__ grad,
                                             const float* __restrict__ meanw,
                                             const float* __restrict__ invw,
                                             const float* __restrict__ T1T,
                                             const float* __restrict__ u1,
                                             const float* __restrict__ b1,
                                             const float* __restrict__ HTp,
                                             const float* __restrict__ bw1,
                                             const float* __restrict__ w2,
                                             const float* __restrict__ bw2,
                                             float* __restrict__ out) {
    __shared__ float redn[2][16];
    __shared__ float bc[2];
    __shared__ float cfs[16];
    int tid = threadIdx.x;
    int wv = tid >> 6, l = tid & 63;
    int row0 = blockIdx.x * 16;
    int c = tid * 4;

    if (tid < 16) {                                   // coeff head
        int b = row0 + tid;
        float z = bw2[0];
#pragma unroll
        for (int j = 0; j < HIDN; ++j) {
            float h = HTp[(size_t)j * BN + b] + HTp[(size_t)(32 + j) * BN + b] +
                      HTp[(size_t)(64 + j) * BN + b] + HTp[(size_t)(96 + j) * BN + b] +
                      bw1[j];
            h = fmaxf(h, 0.f);
            z = fmaf(w2[j], h, z);
        }
        float cf = 1.f / (1.f + expf(-z));
        cfs[tid] = cf;
        out[(size_t)BN * DD + b] = cf;
    }

    float4 u[4][4];
#pragma unroll
    for (int cc = 0; cc < 4; ++cc)
#pragma unroll
        for (int rr = 0; rr < 4; ++rr)
            u[cc][rr] = *(const float4*)(u1 + (size_t)(c + cc) * RK + rr * 4);
    float4 bv = *(const float4*)(b1 + c);
    float4 mv = *(const float4*)(meanw + c);
    float4 iv = *(const float4*)(invw + c);
    __syncthreads();

    for (int row = 0; row < 16; ++row) {
        int b = row0 + row;
        float t[16];
#pragma unroll
        for (int r = 0; r < 16; ++r) t[r] = T1T[(size_t)r * BN + b];  // uniform
        float4 g = *(const float4*)(grad + (size_t)b * DD + c);
        float4 x0;
        x0.x = (g.x - mv.x) * iv.x;
        x0.y = (g.y - mv.y) * iv.y;
        x0.z = (g.z - mv.z) * iv.z;
        x0.w = (g.w - mv.w) * iv.w;
        float4 x2;
        x2.x = fmaxf(dotu(u[0], t, bv.x), 0.f);
        x2.y = fmaxf(dotu(u[1], t, bv.y), 0.f);
        x2.z = fmaxf(dotu(u[2], t, bv.z), 0.f);
        x2.w = fmaxf(dotu(u[3], t, bv.w), 0.f);
        float s0 = x0.x * x0.x + x0.y * x0.y + x0.z * x0.z + x0.w * x0.w;
        float s2 = x2.x * x2.x + x2.y * x2.y + x2.z * x2.z + x2.w * x2.w;
#pragma unroll
        for (int off = 1; off < 64; off <<= 1) {
            s0 += __shfl_xor(s0, off);
            s2 += __shfl_xor(s2, off);
        }
        if (l == 0) {
            redn[0][wv] = s2;
            redn[1][wv] = s0;
        }
        __syncthreads();
        if (tid < 16) {
            float a2 = redn[0][tid], a0 = redn[1][tid];
#pragma unroll
            for (int off = 1; off < 16; off <<= 1) {
                a2 += __shfl_xor(a2, off);
                a0 += __shfl_xor(a0, off);
            }
            if (tid == 0) {
                float xn = sqrtf(a2) + 1e-8f;
                float x0n = sqrtf(a0) + 1e-8f;
                float cf = cfs[row];
                bc[0] = (1.f - cf) * x0n / xn;
                bc[1] = cf;
            }
        }
        __syncthreads();
        float s1 = bc[0], cf = bc[1];
        float4 o;
        o.x = fmaf(s1, x2.x, cf * x0.x);
        o.y = fmaf(s1, x2.y, cf * x0.y);
        o.z = fmaf(s1, x2.z, cf * x0.z);
        o.w = fmaf(s1, x2.w, cf * x0.w);
        *(float4*)(out + (size_t)b * DD + c) = o;
    }
}

extern "C" void kernel_launch(void* const* d_in, const int* in_sizes, int n_in,
                              void* d_out, int out_size, void* d_ws, size_t ws_size,
                              hipStream_t stream) {
    const float* grad = (const float*)d_in[0];
    const float* embed = (const float*)d_in[1];
    const float* u0 = (const float*)d_in[2];
    const float* v0 = (const float*)d_in[3];
    const float* b0 = (const float*)d_in[4];
    const float* u1 = (const float*)d_in[5];
    const float* v1 = (const float*)d_in[6];
    const float* b1 = (const float*)d_in[7];
    const float* w1 = (const float*)d_in[8];
    const float* bw1 = (const float*)d_in[9];
    const float* w2 = (const float*)d_in[10];
    const float* bw2 = (const float*)d_in[11];
    float* out = (float*)d_out;
    float* ws = (float*)d_ws;
    __bf16* v0ph = (__bf16*)(ws + OFF_V0PH);
    __bf16* v0pl = (__bf16*)(ws + OFF_V0PL);
    __bf16* w1h = (__bf16*)(ws + OFF_W1H);
    __bf16* w1l = (__bf16*)(ws + OFF_W1L);

    hipMemsetAsync(ws + OFF_C, 0, 16 * sizeof(float), stream);

    k0w<<<96, 256, 0, stream>>>(w1, w1h, w1l);
    // embed pass first so grad (read by k1a, then k2m/k6fc) stays L3-resident
    k5m<<<2048, 256, 0, stream>>>(embed, w1h, w1l, ws + OFF_HTP);
    k1a<<<512, 256, 0, stream>>>(grad, ws + OFF_PS, ws + OFF_PQ);
    k1bT<<<16, 256, 0, stream>>>(ws + OFF_PS, ws + OFF_PQ, v1, v0,
                                 ws + OFF_MEAN, ws + OFF_INV, ws + OFF_V1T,
                                 v0ph, v0pl, ws + OFF_C);
    k2m<<<2048, 256, 0, stream>>>(grad, v0ph, v0pl, ws + OFF_T0TP);
    k3<<<1024, 256, 0, stream>>>(ws + OFF_T0TP, ws + OFF_C, u0, b0,
                                 ws + OFF_V1T, ws + OFF_T1TP);
    k3r<<<512, 256, 0, stream>>>(ws + OFF_T1TP, ws + OFF_T1T);
    k6fc<<<512, 1024, 0, stream>>>(grad, ws + OFF_MEAN, ws + OFF_INV, ws + OFF_T1T,
                                   u1, b1, ws + OFF_HTP, bw1, w2, bw2, out);
}